// Round 3
// baseline (954.165 us; speedup 1.0000x reference)
//
#include <hip/hip_runtime.h>

#define D 64

// ---------------------------------------------------------------------------
// Pass 1: histogram of dst
// ---------------------------------------------------------------------------
__global__ __launch_bounds__(256)
void hist_kernel(const int* __restrict__ ei, int* __restrict__ counts, int E) {
    int e = blockIdx.x * blockDim.x + threadIdx.x;
    if (e >= E) return;
    atomicAdd(&counts[ei[E + e]], 1);
}

// ---------------------------------------------------------------------------
// Pass 2: exclusive prefix sum over counts[0..n) -> offsets[0..n]
// single block of 1024 threads, ~98 elements per thread
// ---------------------------------------------------------------------------
__global__ __launch_bounds__(1024)
void scan_kernel(const int* __restrict__ counts, int* __restrict__ offsets, int n) {
    __shared__ int part[1024];
    const int tid = threadIdx.x;
    const int C = (n + 1023) / 1024;
    const int base = tid * C;

    int s = 0;
    for (int i = 0; i < C; ++i) {
        int idx = base + i;
        if (idx < n) s += counts[idx];
    }
    part[tid] = s;
    __syncthreads();
    // Hillis-Steele inclusive scan over the 1024 partials
    for (int off = 1; off < 1024; off <<= 1) {
        int v = (tid >= off) ? part[tid - off] : 0;
        __syncthreads();
        part[tid] += v;
        __syncthreads();
    }
    int run = (tid == 0) ? 0 : part[tid - 1];
    for (int i = 0; i < C; ++i) {
        int idx = base + i;
        if (idx <= n) offsets[idx] = run;
        if (idx < n) run += counts[idx];
    }
}

// ---------------------------------------------------------------------------
// Pass 3: scatter edge ids into dst-sorted order
// ---------------------------------------------------------------------------
__global__ __launch_bounds__(256)
void scatter_kernel(const int* __restrict__ ei, int* __restrict__ cursor,
                    int* __restrict__ perm, int E) {
    int e = blockIdx.x * blockDim.x + threadIdx.x;
    if (e >= E) return;
    int pos = atomicAdd(&cursor[ei[E + e]], 1);
    perm[pos] = e;
}

// ---------------------------------------------------------------------------
// Pass 4: per-node aggregation, no atomics.
// one wave per node; lane = feature. h[n] = x[n] + sum_e relu(x[src]+ea[e])
// ---------------------------------------------------------------------------
__global__ __launch_bounds__(256)
void agg_kernel(const float* __restrict__ x,
                const int* __restrict__ ei,
                const float* __restrict__ ea,
                const int* __restrict__ offsets,
                const int* __restrict__ perm,
                float* __restrict__ h, int N, int E) {
    int node = blockIdx.x * (blockDim.x >> 6) + (threadIdx.x >> 6);
    if (node >= N) return;
    int lane = threadIdx.x & 63;

    int beg = offsets[node];
    int end = offsets[node + 1];

    float acc = x[(size_t)node * D + lane];

    int j = beg;
    int e = 0, src = 0;
    if (j < end) { e = perm[j]; src = ei[e]; }
    while (j < end) {
        int e_cur = e, src_cur = src;
        ++j;
        if (j < end) { e = perm[j]; src = ei[e]; }  // prefetch next ids
        float v = x[(size_t)src_cur * D + lane] + ea[(size_t)e_cur * D + lane];
        acc += fmaxf(v, 0.0f);
    }
    h[(size_t)node * D + lane] = acc;
}

// ---------------------------------------------------------------------------
// MLP: out = relu(h W1 + b1) W2 + b2. Weights in VGPRs, readlane broadcast.
// ---------------------------------------------------------------------------
__device__ __forceinline__ float bcast(float v, int k) {
    return __uint_as_float(__builtin_amdgcn_readlane(__float_as_uint(v), k));
}

__global__ __launch_bounds__(256)
void mlp_kernel(const float* __restrict__ h,
                const float* __restrict__ W1, const float* __restrict__ b1,
                const float* __restrict__ W2, const float* __restrict__ b2,
                float* __restrict__ out, int N) {
    const int lane = threadIdx.x & 63;

    float w1[D], w2[D];
#pragma unroll
    for (int k = 0; k < D; ++k) w1[k] = W1[k * D + lane];
#pragma unroll
    for (int k = 0; k < D; ++k) w2[k] = W2[k * D + lane];
    const float bb1 = b1[lane];
    const float bb2 = b2[lane];

    const int wave = blockIdx.x * (blockDim.x >> 6) + (threadIdx.x >> 6);
    const int nwaves = gridDim.x * (blockDim.x >> 6);

    for (int row = wave * 2; row < N; row += nwaves * 2) {
        const int rowB = row + 1;
        const bool hasB = rowB < N;

        float va = h[(size_t)row * D + lane];
        float vb = hasB ? h[(size_t)rowB * D + lane] : 0.0f;

        float a0 = 0.f, a1 = 0.f, c0 = 0.f, c1 = 0.f;
#pragma unroll
        for (int k = 0; k < D; k += 2) {
            float sa0 = bcast(va, k);
            float sa1 = bcast(va, k + 1);
            float sb0 = bcast(vb, k);
            float sb1 = bcast(vb, k + 1);
            a0 = fmaf(sa0, w1[k],     a0);
            a1 = fmaf(sa1, w1[k + 1], a1);
            c0 = fmaf(sb0, w1[k],     c0);
            c1 = fmaf(sb1, w1[k + 1], c1);
        }
        float ra = fmaxf(a0 + a1 + bb1, 0.0f);
        float rb = fmaxf(c0 + c1 + bb1, 0.0f);

        a0 = 0.f; a1 = 0.f; c0 = 0.f; c1 = 0.f;
#pragma unroll
        for (int k = 0; k < D; k += 2) {
            float sa0 = bcast(ra, k);
            float sa1 = bcast(ra, k + 1);
            float sb0 = bcast(rb, k);
            float sb1 = bcast(rb, k + 1);
            a0 = fmaf(sa0, w2[k],     a0);
            a1 = fmaf(sa1, w2[k + 1], a1);
            c0 = fmaf(sb0, w2[k],     c0);
            c1 = fmaf(sb1, w2[k + 1], c1);
        }
        out[(size_t)row * D + lane] = a0 + a1 + bb2;
        if (hasB) out[(size_t)rowB * D + lane] = c0 + c1 + bb2;
    }
}

extern "C" void kernel_launch(void* const* d_in, const int* in_sizes, int n_in,
                              void* d_out, int out_size, void* d_ws, size_t ws_size,
                              hipStream_t stream) {
    const float* x  = (const float*)d_in[0];
    const int*   ei = (const int*)d_in[1];
    const float* ea = (const float*)d_in[2];
    const float* W1 = (const float*)d_in[3];
    const float* b1 = (const float*)d_in[4];
    const float* W2 = (const float*)d_in[5];
    const float* b2 = (const float*)d_in[6];
    float* out = (float*)d_out;

    int N = in_sizes[0] / D;      // 100000
    int E = in_sizes[1] / 2;      // 1200000

    // ---- workspace layout ----
    char* ws = (char*)d_ws;
    float* h       = (float*)ws;                        ws += (size_t)N * D * sizeof(float); // 25.6 MB
    int*   counts  = (int*)ws;                          ws += (size_t)(N + 1) * sizeof(int);
    int*   offsets = (int*)ws;                          ws += (size_t)(N + 1) * sizeof(int);
    int*   cursor  = (int*)ws;                          ws += (size_t)N * sizeof(int);
    int*   perm    = (int*)ws;                          ws += (size_t)E * sizeof(int);       // 4.8 MB

    // 1) histogram
    hipMemsetAsync(counts, 0, (size_t)(N + 1) * sizeof(int), stream);
    int eb = (E + 255) / 256;
    hipLaunchKernelGGL(hist_kernel, dim3(eb), dim3(256), 0, stream, ei, counts, E);

    // 2) prefix sum
    hipLaunchKernelGGL(scan_kernel, dim3(1), dim3(1024), 0, stream, counts, offsets, N);

    // 3) scatter perm (cursor starts at offsets)
    hipMemcpyAsync(cursor, offsets, (size_t)N * sizeof(int), hipMemcpyDeviceToDevice, stream);
    hipLaunchKernelGGL(scatter_kernel, dim3(eb), dim3(256), 0, stream, ei, cursor, perm, E);

    // 4) aggregate (4 nodes per 256-thread block)
    int ab = (N + 3) / 4;
    hipLaunchKernelGGL(agg_kernel, dim3(ab), dim3(256), 0, stream,
                       x, ei, ea, offsets, perm, h, N, E);

    // 5) MLP
    hipLaunchKernelGGL(mlp_kernel, dim3(1024), dim3(256), 0, stream,
                       h, W1, b1, W2, b2, out, N);
}

// Round 4
// 655.146 us; speedup vs baseline: 1.4564x; 1.4564x over previous
//
#include <hip/hip_runtime.h>

#define D 64

// ---------------------------------------------------------------------------
// Pass 1: histogram of dst
// ---------------------------------------------------------------------------
__global__ __launch_bounds__(256)
void hist_kernel(const int* __restrict__ ei, int* __restrict__ counts, int E) {
    int e = blockIdx.x * blockDim.x + threadIdx.x;
    if (e >= E) return;
    atomicAdd(&counts[ei[E + e]], 1);
}

// ---------------------------------------------------------------------------
// Pass 2a: per-block (256-counter) sums
// ---------------------------------------------------------------------------
__global__ __launch_bounds__(256)
void block_sums_kernel(const int* __restrict__ counts, int* __restrict__ partials,
                       int n) {
    int idx = blockIdx.x * 256 + threadIdx.x;
    int v = (idx < n) ? counts[idx] : 0;
    // wave reduce
    int lane = threadIdx.x & 63;
#pragma unroll
    for (int off = 1; off < 64; off <<= 1) {
        int t = __shfl_down(v, off);
        v += t;
    }
    __shared__ int ws[4];
    if (lane == 0) ws[threadIdx.x >> 6] = v;
    __syncthreads();
    if (threadIdx.x == 0)
        partials[blockIdx.x] = ws[0] + ws[1] + ws[2] + ws[3];
}

// ---------------------------------------------------------------------------
// Pass 2b: exclusive scan of the (<=512) block partials, one block
// ---------------------------------------------------------------------------
__global__ __launch_bounds__(512)
void scan_partials_kernel(const int* __restrict__ partials,
                          int* __restrict__ pprefix, int nb) {
    __shared__ int sh[512];
    int tid = threadIdx.x;
    sh[tid] = (tid < nb) ? partials[tid] : 0;
    __syncthreads();
#pragma unroll
    for (int off = 1; off < 512; off <<= 1) {
        int v = (tid >= off) ? sh[tid - off] : 0;
        __syncthreads();
        sh[tid] += v;
        __syncthreads();
    }
    if (tid < nb) pprefix[tid] = (tid == 0) ? 0 : sh[tid - 1];
}

// ---------------------------------------------------------------------------
// Pass 2c: offsets[idx] = pprefix[block] + exclusive_scan_in_block(counts)
// ---------------------------------------------------------------------------
__global__ __launch_bounds__(256)
void write_offsets_kernel(const int* __restrict__ counts,
                          const int* __restrict__ pprefix,
                          int* __restrict__ offsets, int n, int E) {
    int idx = blockIdx.x * 256 + threadIdx.x;
    int v = (idx < n) ? counts[idx] : 0;
    int lane = threadIdx.x & 63;
    int wv = threadIdx.x >> 6;

    int s = v;
#pragma unroll
    for (int off = 1; off < 64; off <<= 1) {
        int t = __shfl_up(s, off);
        if (lane >= off) s += t;
    }
    __shared__ int wsum[4];
    if (lane == 63) wsum[wv] = s;
    __syncthreads();
    int base = 0;
    for (int w = 0; w < wv; ++w) base += wsum[w];
    int excl = base + s - v;
    if (idx < n) offsets[idx] = pprefix[blockIdx.x] + excl;
    if (idx == n) offsets[n] = E;
    if (blockIdx.x == 0 && threadIdx.x == 0 && n % 256 != 0) offsets[n] = E;
}

// ---------------------------------------------------------------------------
// Pass 3: scatter (e, src) pairs into dst-sorted order
// ---------------------------------------------------------------------------
__global__ __launch_bounds__(256)
void scatter_kernel(const int* __restrict__ ei, int* __restrict__ cursor,
                    int2* __restrict__ perm2, int E) {
    int e = blockIdx.x * blockDim.x + threadIdx.x;
    if (e >= E) return;
    int src = ei[e];
    int dst = ei[E + e];
    int pos = atomicAdd(&cursor[dst], 1);
    perm2[pos] = make_int2(e, src);
}

// ---------------------------------------------------------------------------
// Pass 4: per-node aggregation, no atomics, 4-deep load pipelining.
// one wave per node; lane = feature. h[n] = x[n] + sum_e relu(x[src]+ea[e])
// ---------------------------------------------------------------------------
__global__ __launch_bounds__(256)
void agg_kernel(const float* __restrict__ x,
                const float* __restrict__ ea,
                const int* __restrict__ offsets,
                const int2* __restrict__ perm2,
                float* __restrict__ h, int N) {
    int node = blockIdx.x * (blockDim.x >> 6) + (threadIdx.x >> 6);
    if (node >= N) return;
    int lane = threadIdx.x & 63;

    int beg = offsets[node];
    int end = offsets[node + 1];
    int cnt = end - beg;
    const int2* pp = perm2 + beg;

    float acc = x[(size_t)node * D + lane];

    int j = 0;
    for (; j + 4 <= cnt; j += 4) {
        int2 p0 = pp[j];
        int2 p1 = pp[j + 1];
        int2 p2 = pp[j + 2];
        int2 p3 = pp[j + 3];
        float e0 = ea[(size_t)p0.x * D + lane];
        float x0 = x[(size_t)p0.y * D + lane];
        float e1 = ea[(size_t)p1.x * D + lane];
        float x1 = x[(size_t)p1.y * D + lane];
        float e2 = ea[(size_t)p2.x * D + lane];
        float x2 = x[(size_t)p2.y * D + lane];
        float e3 = ea[(size_t)p3.x * D + lane];
        float x3 = x[(size_t)p3.y * D + lane];
        acc += fmaxf(x0 + e0, 0.0f);
        acc += fmaxf(x1 + e1, 0.0f);
        acc += fmaxf(x2 + e2, 0.0f);
        acc += fmaxf(x3 + e3, 0.0f);
    }
    for (; j < cnt; ++j) {
        int2 p = pp[j];
        float ev = ea[(size_t)p.x * D + lane];
        float xv = x[(size_t)p.y * D + lane];
        acc += fmaxf(xv + ev, 0.0f);
    }
    h[(size_t)node * D + lane] = acc;
}

// ---------------------------------------------------------------------------
// MLP: out = relu(h W1 + b1) W2 + b2. Weights in VGPRs, readlane broadcast.
// ---------------------------------------------------------------------------
__device__ __forceinline__ float bcast(float v, int k) {
    return __uint_as_float(__builtin_amdgcn_readlane(__float_as_uint(v), k));
}

__global__ __launch_bounds__(256)
void mlp_kernel(const float* __restrict__ h,
                const float* __restrict__ W1, const float* __restrict__ b1,
                const float* __restrict__ W2, const float* __restrict__ b2,
                float* __restrict__ out, int N) {
    const int lane = threadIdx.x & 63;

    float w1[D], w2[D];
#pragma unroll
    for (int k = 0; k < D; ++k) w1[k] = W1[k * D + lane];
#pragma unroll
    for (int k = 0; k < D; ++k) w2[k] = W2[k * D + lane];
    const float bb1 = b1[lane];
    const float bb2 = b2[lane];

    const int wave = blockIdx.x * (blockDim.x >> 6) + (threadIdx.x >> 6);
    const int nwaves = gridDim.x * (blockDim.x >> 6);

    for (int row = wave * 2; row < N; row += nwaves * 2) {
        const int rowB = row + 1;
        const bool hasB = rowB < N;

        float va = h[(size_t)row * D + lane];
        float vb = hasB ? h[(size_t)rowB * D + lane] : 0.0f;

        float a0 = 0.f, a1 = 0.f, c0 = 0.f, c1 = 0.f;
#pragma unroll
        for (int k = 0; k < D; k += 2) {
            float sa0 = bcast(va, k);
            float sa1 = bcast(va, k + 1);
            float sb0 = bcast(vb, k);
            float sb1 = bcast(vb, k + 1);
            a0 = fmaf(sa0, w1[k],     a0);
            a1 = fmaf(sa1, w1[k + 1], a1);
            c0 = fmaf(sb0, w1[k],     c0);
            c1 = fmaf(sb1, w1[k + 1], c1);
        }
        float ra = fmaxf(a0 + a1 + bb1, 0.0f);
        float rb = fmaxf(c0 + c1 + bb1, 0.0f);

        a0 = 0.f; a1 = 0.f; c0 = 0.f; c1 = 0.f;
#pragma unroll
        for (int k = 0; k < D; k += 2) {
            float sa0 = bcast(ra, k);
            float sa1 = bcast(ra, k + 1);
            float sb0 = bcast(rb, k);
            float sb1 = bcast(rb, k + 1);
            a0 = fmaf(sa0, w2[k],     a0);
            a1 = fmaf(sa1, w2[k + 1], a1);
            c0 = fmaf(sb0, w2[k],     c0);
            c1 = fmaf(sb1, w2[k + 1], c1);
        }
        out[(size_t)row * D + lane] = a0 + a1 + bb2;
        if (hasB) out[(size_t)rowB * D + lane] = c0 + c1 + bb2;
    }
}

extern "C" void kernel_launch(void* const* d_in, const int* in_sizes, int n_in,
                              void* d_out, int out_size, void* d_ws, size_t ws_size,
                              hipStream_t stream) {
    const float* x  = (const float*)d_in[0];
    const int*   ei = (const int*)d_in[1];
    const float* ea = (const float*)d_in[2];
    const float* W1 = (const float*)d_in[3];
    const float* b1 = (const float*)d_in[4];
    const float* W2 = (const float*)d_in[5];
    const float* b2 = (const float*)d_in[6];
    float* out = (float*)d_out;

    int N = in_sizes[0] / D;      // 100000
    int E = in_sizes[1] / 2;      // 1200000

    int NB = (N + 255) / 256;     // 391 counter blocks

    // ---- workspace layout ----
    char* ws = (char*)d_ws;
    float* h        = (float*)ws;  ws += (size_t)N * D * sizeof(float); // 25.6 MB
    int*   counts   = (int*)ws;    ws += (size_t)N * sizeof(int);
    int*   offsets  = (int*)ws;    ws += (size_t)(N + 1) * sizeof(int);
    int*   cursor   = (int*)ws;    ws += (size_t)N * sizeof(int);
    int*   partials = (int*)ws;    ws += (size_t)NB * sizeof(int);
    int*   pprefix  = (int*)ws;    ws += (size_t)NB * sizeof(int);
    int2*  perm2    = (int2*)ws;   ws += (size_t)E * sizeof(int2);      // 9.6 MB

    int eb = (E + 255) / 256;

    // 1) histogram
    hipMemsetAsync(counts, 0, (size_t)N * sizeof(int), stream);
    hipLaunchKernelGGL(hist_kernel, dim3(eb), dim3(256), 0, stream, ei, counts, E);

    // 2) three-stage exclusive scan -> offsets[0..N]
    hipLaunchKernelGGL(block_sums_kernel, dim3(NB), dim3(256), 0, stream,
                       counts, partials, N);
    hipLaunchKernelGGL(scan_partials_kernel, dim3(1), dim3(512), 0, stream,
                       partials, pprefix, NB);
    hipLaunchKernelGGL(write_offsets_kernel, dim3(NB), dim3(256), 0, stream,
                       counts, pprefix, offsets, N, E);

    // 3) scatter (e, src) into dst-sorted order
    hipMemcpyAsync(cursor, offsets, (size_t)N * sizeof(int),
                   hipMemcpyDeviceToDevice, stream);
    hipLaunchKernelGGL(scatter_kernel, dim3(eb), dim3(256), 0, stream,
                       ei, cursor, perm2, E);

    // 4) aggregate (4 nodes / block)
    int ab = (N + 3) / 4;
    hipLaunchKernelGGL(agg_kernel, dim3(ab), dim3(256), 0, stream,
                       x, ea, offsets, perm2, h, N);

    // 5) MLP
    hipLaunchKernelGGL(mlp_kernel, dim3(1024), dim3(256), 0, stream,
                       h, W1, b1, W2, b2, out, N);
}